// Round 3
// baseline (39.704 us; speedup 1.0000x reference)
//
#include <hip/hip_runtime.h>
#include <float.h>

#define BATCH   8
#define NPTS    4096
#define THREADS 1024
#define NWAVE   (THREADS / 64)            // 16 waves
#define XTILE   256                       // x-points per block
#define P       4                         // x-points per lane (XTILE / 64)
#define YPW     (NPTS / NWAVE)            // 256 y per wave
#define BLOCKS_PER_DIR (BATCH * (NPTS / XTILE))   // 8*16 = 128
#define TOTAL_BLOCKS   (2 * BLOCKS_PER_DIR)       // 256

// Block = one (dir, batch, x-tile of 256). Lane l owns x {l, l+64, l+128, l+192}.
// Wave w scans y-chunk w (256 y) of all 4096 y staged once in LDS as
// (-2y0,-2y1,-2y2,|y|^2). Inner loop: 1 wave-uniform ds_read_b128 per y feeds
// 4 dot-chains; 3 fma + 0.5 min3 per pair. |x|^2 folded in the epilogue.
// Final mean fused via last-block-done (counter in ws, device-scope fences).
__global__ __launch_bounds__(THREADS) void chamfer_kernel(
    const float* __restrict__ A, const float* __restrict__ Bp,
    float* __restrict__ partials, int* __restrict__ counter,
    float* __restrict__ out)
{
    __shared__ float4 ys[NPTS];              // 64 KB transformed y
    __shared__ float  smin[NWAVE][XTILE];    // 16 KB per-wave mins
    __shared__ float  sxs[XTILE];            // |x|^2
    __shared__ float  wsum[NWAVE];           // per-wave partial sums
    __shared__ int    slast;

    const int bid  = blockIdx.x;
    const int dir  = bid >> 7;
    const int sub  = bid & 127;
    const int b    = sub >> 4;
    const int tile = sub & 15;
    const int tid  = threadIdx.x;
    const int lane = tid & 63;
    const int wave = tid >> 6;

    const float* xbase = (dir == 0 ? A : Bp) + (size_t)b * NPTS * 3;
    const float* ybase = (dir == 0 ? Bp : A) + (size_t)b * NPTS * 3;

    // ---- stage + transform y (scalar loads, L2-resident: 48 KB/block) ----
    #pragma unroll
    for (int p = tid; p < NPTS; p += THREADS) {
        const float y0 = ybase[3 * p], y1 = ybase[3 * p + 1], y2 = ybase[3 * p + 2];
        ys[p] = make_float4(-2.f * y0, -2.f * y1, -2.f * y2,
                            y0 * y0 + y1 * y1 + y2 * y2);
    }

    // ---- x into registers (same 4 x for every wave) ----
    float x0[P], x1[P], x2[P], mn[P];
    #pragma unroll
    for (int p = 0; p < P; ++p) {
        const int xi = tile * XTILE + p * 64 + lane;
        x0[p] = xbase[xi * 3 + 0];
        x1[p] = xbase[xi * 3 + 1];
        x2[p] = xbase[xi * 3 + 2];
        mn[p] = FLT_MAX;
        if (wave == 0)
            sxs[p * 64 + lane] = x0[p] * x0[p] + x1[p] * x1[p] + x2[p] * x2[p];
    }
    __syncthreads();

    // ---- main loop: wave w scans its 256-y chunk ----
    const float4* yw_ptr = &ys[wave * YPW];
    #pragma unroll 4
    for (int i = 0; i < YPW; i += 2) {
        const float4 a = yw_ptr[i];
        const float4 c = yw_ptr[i + 1];
        #pragma unroll
        for (int p = 0; p < P; ++p) {
            const float da = fmaf(x0[p], a.x, fmaf(x1[p], a.y, fmaf(x2[p], a.z, a.w)));
            const float dc = fmaf(x0[p], c.x, fmaf(x1[p], c.y, fmaf(x2[p], c.z, c.w)));
            mn[p] = fminf(mn[p], fminf(da, dc));   // v_min3_f32
        }
    }
    #pragma unroll
    for (int p = 0; p < P; ++p)
        smin[wave][p * 64 + lane] = mn[p];
    __syncthreads();

    // ---- epilogue: 16-way min per x, clamp, wave-shuffle sum ----
    if (tid < XTILE) {
        float m = smin[0][tid];
        #pragma unroll
        for (int w = 1; w < NWAVE; ++w) m = fminf(m, smin[w][tid]);
        m = fmaxf(sxs[tid] + m, 0.0f);
        #pragma unroll
        for (int off = 32; off > 0; off >>= 1)
            m += __shfl_down(m, off, 64);
        if (lane == 0) wsum[wave] = m;      // waves 0..3 active here
    }
    __syncthreads();

    if (tid == 0) {
        partials[bid] = wsum[0] + wsum[1] + wsum[2] + wsum[3];
        __threadfence();                                   // release partial
        const int old = atomicAdd(counter, 1);             // device scope
        slast = (old == TOTAL_BLOCKS - 1) ? 1 : 0;
    }
    __syncthreads();

    // ---- last block: deterministic fixed-order final reduction ----
    if (slast) {
        __threadfence();                                   // acquire partials
        float v = (tid < TOTAL_BLOCKS) ? partials[tid] : 0.0f;
        #pragma unroll
        for (int off = 32; off > 0; off >>= 1)
            v += __shfl_down(v, off, 64);
        if (lane == 0) wsum[wave] = v;                     // waves 0..3 hold sums
        __syncthreads();
        if (tid == 0)
            out[0] = (wsum[0] + wsum[1] + wsum[2] + wsum[3]) * (1.0f / (BATCH * NPTS));
    }
}

extern "C" void kernel_launch(void* const* d_in, const int* in_sizes, int n_in,
                              void* d_out, int out_size, void* d_ws, size_t ws_size,
                              hipStream_t stream) {
    const float* A = (const float*)d_in[0];   // coor_recon [8,4096,3]
    const float* B = (const float*)d_in[1];   // pc_gd      [8,4096,3]
    float* partials = (float*)d_ws;           // [0..256): block partials
    int*   counter  = (int*)d_ws + TOTAL_BLOCKS;
    float* out = (float*)d_out;

    hipMemsetAsync(counter, 0, sizeof(int), stream);       // graph-capturable
    chamfer_kernel<<<TOTAL_BLOCKS, THREADS, 0, stream>>>(A, B, partials, counter, out);
}

// Round 4
// 28.393 us; speedup vs baseline: 1.3984x; 1.3984x over previous
//
#include <hip/hip_runtime.h>
#include <float.h>

typedef float v2f __attribute__((ext_vector_type(2)));

#define BATCH   8
#define NPTS    4096
#define THREADS 512
#define NWAVE   (THREADS / 64)            // 8 waves
#define XTILE   256                       // x-points per block
#define P       4                         // x-points per lane
#define YPW     (NPTS / NWAVE)            // 512 y per wave
#define PPW     (YPW / 2)                 // 256 y-pairs per wave
#define NPAIR   (NPTS / 2)                // 2048 y-pairs total
#define BLOCKS_PER_DIR (BATCH * (NPTS / XTILE))   // 128
#define TOTAL_BLOCKS   (2 * BLOCKS_PER_DIR)       // 256

__device__ __forceinline__ float min3f(float a, float b, float c) {
    float d;
    asm("v_min3_f32 %0, %1, %2, %3" : "=v"(d) : "v"(a), "v"(b), "v"(c));
    return d;
}

// Block = one (dir, batch, x-tile of 256). Lane l owns x {l, l+64, l+128, l+192}.
// y staged once in LDS, PAIR-PACKED for v_pk_fma_f32:
//   ysAB[k] = (-2y0[2k], -2y0[2k+1], -2y1[2k], -2y1[2k+1])
//   ysCW[k] = (-2y2[2k], -2y2[2k+1], |y[2k]|^2, |y[2k+1]|^2)
// Inner loop per y-pair per lane: 2 broadcast ds_read_b128 + P*(3 pk_fma + 1 min3)
// = 2.0 VALU/pair. |x|^2 folded in the epilogue (min is translation-invariant).
__global__ __launch_bounds__(THREADS) void chamfer_min_kernel(
    const float* __restrict__ A, const float* __restrict__ Bp,
    float* __restrict__ partials)
{
    __shared__ float4 ysAB[NPAIR];           // 32 KB
    __shared__ float4 ysCW[NPAIR];           // 32 KB
    __shared__ float  smin[NWAVE][XTILE];    // 8 KB
    __shared__ float  sxs[XTILE];            // |x|^2
    __shared__ float  rsum[XTILE];           // sum tree

    const int bid  = blockIdx.x;
    const int dir  = bid >> 7;
    const int sub  = bid & 127;
    const int b    = sub >> 4;
    const int tile = sub & 15;
    const int tid  = threadIdx.x;
    const int lane = tid & 63;
    const int wave = tid >> 6;

    const float* xbase = (dir == 0 ? A : Bp) + (size_t)b * NPTS * 3;
    const float* ybase = (dir == 0 ? Bp : A) + (size_t)b * NPTS * 3;

    // ---- stage y: thread t handles points 4t..4t+3 = 3 aligned float4 loads ----
    const float4* yg4 = (const float4*)ybase;
    #pragma unroll
    for (int j = 0; j < NPTS / (4 * THREADS); ++j) {       // 2 iterations
        const int t  = tid + j * THREADS;
        const float4 f0 = yg4[3 * t + 0];
        const float4 f1 = yg4[3 * t + 1];
        const float4 f2 = yg4[3 * t + 2];
        // points: p0=(f0.x,f0.y,f0.z) p1=(f0.w,f1.x,f1.y) p2=(f1.z,f1.w,f2.x) p3=(f2.y,f2.z,f2.w)
        const int k0 = 2 * t;
        ysAB[k0]     = make_float4(-2.f * f0.x, -2.f * f0.w, -2.f * f0.y, -2.f * f1.x);
        ysCW[k0]     = make_float4(-2.f * f0.z, -2.f * f1.y,
                                   f0.x * f0.x + f0.y * f0.y + f0.z * f0.z,
                                   f0.w * f0.w + f1.x * f1.x + f1.y * f1.y);
        ysAB[k0 + 1] = make_float4(-2.f * f1.z, -2.f * f2.y, -2.f * f1.w, -2.f * f2.z);
        ysCW[k0 + 1] = make_float4(-2.f * f2.x, -2.f * f2.w,
                                   f1.z * f1.z + f1.w * f1.w + f2.x * f2.x,
                                   f2.y * f2.y + f2.z * f2.z + f2.w * f2.w);
    }

    // ---- x into registers, splatted for packed math ----
    v2f X0[P], X1[P], X2[P];
    float mn[P];
    #pragma unroll
    for (int p = 0; p < P; ++p) {
        const int xi = tile * XTILE + p * 64 + lane;
        const float x0 = xbase[xi * 3 + 0];
        const float x1 = xbase[xi * 3 + 1];
        const float x2 = xbase[xi * 3 + 2];
        X0[p] = (v2f){x0, x0};
        X1[p] = (v2f){x1, x1};
        X2[p] = (v2f){x2, x2};
        mn[p] = FLT_MAX;
        if (wave == 0)
            sxs[p * 64 + lane] = x0 * x0 + x1 * x1 + x2 * x2;
    }
    __syncthreads();

    // ---- main loop: wave w scans its 256 y-pairs ----
    const float4* abp = &ysAB[wave * PPW];
    const float4* cwp = &ysCW[wave * PPW];
    #pragma unroll 4
    for (int k = 0; k < PPW; ++k) {
        const float4 ab = abp[k];            // broadcast ds_read_b128
        const float4 cw = cwp[k];
        const v2f Av = (v2f){ab.x, ab.y};
        const v2f Bv = (v2f){ab.z, ab.w};
        const v2f Cv = (v2f){cw.x, cw.y};
        const v2f Wv = (v2f){cw.z, cw.w};
        #pragma unroll
        for (int p = 0; p < P; ++p) {
            const v2f d = __builtin_elementwise_fma(X0[p], Av,
                          __builtin_elementwise_fma(X1[p], Bv,
                          __builtin_elementwise_fma(X2[p], Cv, Wv)));
            mn[p] = min3f(mn[p], d[0], d[1]);
        }
    }

    #pragma unroll
    for (int p = 0; p < P; ++p)
        smin[wave][p * 64 + lane] = mn[p];
    __syncthreads();

    // ---- epilogue: 8-way min per x, add |x|^2, clamp, deterministic sum ----
    if (tid < XTILE) {
        float m = smin[0][tid];
        #pragma unroll
        for (int w = 1; w < NWAVE; ++w) m = fminf(m, smin[w][tid]);
        rsum[tid] = fmaxf(sxs[tid] + m, 0.0f);
    }
    __syncthreads();
    #pragma unroll
    for (int s = XTILE / 2; s > 0; s >>= 1) {
        if (tid < s) rsum[tid] += rsum[tid + s];
        __syncthreads();
    }
    if (tid == 0) partials[bid] = rsum[0];
}

// Deterministic fixed-order reduction of 256 block partials.
__global__ __launch_bounds__(256) void chamfer_final_kernel(
    const float* __restrict__ partials, float* __restrict__ out)
{
    __shared__ float r[256];
    const int tid = threadIdx.x;
    r[tid] = partials[tid];
    __syncthreads();
    #pragma unroll
    for (int s = 128; s > 0; s >>= 1) {
        if (tid < s) r[tid] += r[tid + s];
        __syncthreads();
    }
    if (tid == 0) out[0] = r[0] * (1.0f / (BATCH * NPTS));
}

extern "C" void kernel_launch(void* const* d_in, const int* in_sizes, int n_in,
                              void* d_out, int out_size, void* d_ws, size_t ws_size,
                              hipStream_t stream) {
    const float* A = (const float*)d_in[0];   // coor_recon [8,4096,3]
    const float* B = (const float*)d_in[1];   // pc_gd      [8,4096,3]
    float* partials = (float*)d_ws;           // 256 floats, fully rewritten each call
    float* out = (float*)d_out;

    chamfer_min_kernel<<<TOTAL_BLOCKS, THREADS, 0, stream>>>(A, B, partials);
    chamfer_final_kernel<<<1, 256, 0, stream>>>(partials, out);
}